// Round 1
// baseline (147.487 us; speedup 1.0000x reference)
//
#include <hip/hip_runtime.h>

typedef unsigned short ushort_t;
typedef __attribute__((ext_vector_type(8))) short short8;
typedef __attribute__((ext_vector_type(4))) short short4v;
typedef __attribute__((ext_vector_type(4))) float float4v;

#define Bn 32
#define Nn 2048
#define Cn 8
#define Fn 128
#define On 128
#define Kn 384   // 3*F
#define MT 64    // rows per workgroup
#define LDSK 392 // Kn + 8 pad (in shorts); row stride 784 B (16B-aligned, +4 banks/row)

// float -> bf16 bits, round-to-nearest-even
__device__ __forceinline__ ushort_t f2bf(float x) {
  unsigned u = __float_as_uint(x);
  u += 0x7fffu + ((u >> 16) & 1u);
  return (ushort_t)(u >> 16);
}

// Pack concat(w_t, w_r, w_l) transposed: wcT[o][k], k in [0,384), bf16 bits.
__global__ void prep_w_kernel(const float* __restrict__ w_t,
                              const float* __restrict__ w_l,
                              const float* __restrict__ w_r,
                              ushort_t* __restrict__ wcT) {
  int i = blockIdx.x * blockDim.x + threadIdx.x;
  if (i >= On * Kn) return;
  int o = i / Kn;
  int k = i - o * Kn;
  const float* src = (k < Fn) ? w_t : (k < 2 * Fn) ? w_r : w_l;
  int f = k & (Fn - 1);
  wcT[i] = f2bf(src[f * On + o]);
}

__global__ __launch_bounds__(256)
void tree_conv_kernel(const float* __restrict__ nodes,
                      const int* __restrict__ children,
                      const ushort_t* __restrict__ wcT,
                      const float* __restrict__ bias,
                      float* __restrict__ out) {
  __shared__ __align__(16) ushort_t agg[MT * LDSK];

  const int tid = threadIdx.x;

  // ---------------- Phase A: build bf16 agg tile [64 rows][384] in LDS ------
  {
    const int row = tid >> 2;            // 0..63
    const int fc = (tid & 3) * 32;       // f-chunk start (32 floats per thread)
    const int g = blockIdx.x * MT + row; // global row in [0, 65536)
    const int base_row = g & ~(Nn - 1);  // b * Nn

    const int4* chv = (const int4*)(children + g * Cn);
    int4 ca = chv[0], cb = chv[1];
    int idx[Cn] = {ca.x, ca.y, ca.z, ca.w, cb.x, cb.y, cb.z, cb.w};

    int ns = 0;
#pragma unroll
    for (int c = 0; c < Cn; ++c) ns += (idx[c] != 0);
    const float denom = (ns > 1) ? (float)(ns - 1) : 1.0f;

    float crv[Cn], clv[Cn];
#pragma unroll
    for (int c = 0; c < Cn; ++c) {
      float m = (idx[c] != 0) ? 1.0f : 0.0f;
      float cr0 = (ns == 1) ? ((c == 0) ? 0.5f : 0.0f) : ((float)c / denom);
      float cr = cr0 * m;          // zero coeff when child idx==0 (zero-vector)
      crv[c] = cr;
      clv[c] = (1.0f - cr) * m;
    }

    ushort_t* arow = agg + row * LDSK;

    // self -> k [0,128)
    const float4v* sp = (const float4v*)(nodes + (size_t)g * Fn + fc);
#pragma unroll
    for (int j = 0; j < 8; ++j) {
      float4v v = sp[j];
      short4v s = {(short)f2bf(v.x), (short)f2bf(v.y),
                   (short)f2bf(v.z), (short)f2bf(v.w)};
      *(short4v*)(arow + fc + j * 4) = s;
    }

    // children -> r (k [128,256)) and l (k [256,384))
    float4v r[8], l[8];
    const float4v z = {0.f, 0.f, 0.f, 0.f};
#pragma unroll
    for (int j = 0; j < 8; ++j) { r[j] = z; l[j] = z; }

#pragma unroll
    for (int c = 0; c < Cn; ++c) {
      // idx==0 reads nodes row 0 of batch, but coeffs are 0 -> contributes 0
      const float4v* cp =
          (const float4v*)(nodes + (size_t)(base_row + idx[c]) * Fn + fc);
      const float cr = crv[c], cl = clv[c];
#pragma unroll
      for (int j = 0; j < 8; ++j) {
        float4v v = cp[j];
        r[j] += cr * v;
        l[j] += cl * v;
      }
    }

#pragma unroll
    for (int j = 0; j < 8; ++j) {
      float4v v = r[j];
      short4v s = {(short)f2bf(v.x), (short)f2bf(v.y),
                   (short)f2bf(v.z), (short)f2bf(v.w)};
      *(short4v*)(arow + Fn + fc + j * 4) = s;
      v = l[j];
      short4v t = {(short)f2bf(v.x), (short)f2bf(v.y),
                   (short)f2bf(v.z), (short)f2bf(v.w)};
      *(short4v*)(arow + 2 * Fn + fc + j * 4) = t;
    }
  }

  // ---------------- B fragments: held in registers, reused over 4 subtiles --
  const int lane = tid & 63;
  const int wave = tid >> 6;   // 0..3, owns cols [wave*32, wave*32+32)
  const int l15 = lane & 15;
  const int quad = lane >> 4;

  short8 bfrag[2][12];
#pragma unroll
  for (int ct = 0; ct < 2; ++ct) {
    const ushort_t* bp = wcT + (size_t)(wave * 32 + ct * 16 + l15) * Kn + quad * 8;
#pragma unroll
    for (int ks = 0; ks < 12; ++ks)
      bfrag[ct][ks] = *(const short8*)(bp + ks * 32);
  }

  const float bias0 = bias[wave * 32 + l15];
  const float bias1 = bias[wave * 32 + 16 + l15];

  __syncthreads();

  // ---------------- Phase B: MFMA over 4 row-subtiles of 16 ----------------
#pragma unroll 1
  for (int st = 0; st < 4; ++st) {
    const ushort_t* ar = agg + (st * 16 + l15) * LDSK + quad * 8;
    float4v acc0 = {0.f, 0.f, 0.f, 0.f};
    float4v acc1 = {0.f, 0.f, 0.f, 0.f};
#pragma unroll
    for (int ks = 0; ks < 12; ++ks) {
      short8 af = *(const short8*)(ar + ks * 32);
      acc0 = __builtin_amdgcn_mfma_f32_16x16x32_bf16(af, bfrag[0][ks], acc0, 0, 0, 0);
      acc1 = __builtin_amdgcn_mfma_f32_16x16x32_bf16(af, bfrag[1][ks], acc1, 0, 0, 0);
    }
    const int grow0 = blockIdx.x * MT + st * 16 + quad * 4;
    const int col0 = wave * 32 + l15;
#pragma unroll
    for (int r2 = 0; r2 < 4; ++r2) {
      float v0 = acc0[r2] + bias0;
      float v1 = acc1[r2] + bias1;
      out[(size_t)(grow0 + r2) * On + col0] = fmaxf(v0, 0.f);
      out[(size_t)(grow0 + r2) * On + col0 + 16] = fmaxf(v1, 0.f);
    }
  }
}

extern "C" void kernel_launch(void* const* d_in, const int* in_sizes, int n_in,
                              void* d_out, int out_size, void* d_ws, size_t ws_size,
                              hipStream_t stream) {
  const float* nodes = (const float*)d_in[0];
  const int* children = (const int*)d_in[1];
  const float* w_t = (const float*)d_in[2];
  const float* w_l = (const float*)d_in[3];
  const float* w_r = (const float*)d_in[4];
  const float* bias = (const float*)d_in[5];
  float* out = (float*)d_out;
  ushort_t* wcT = (ushort_t*)d_ws;  // 128*384*2 = 96 KiB

  prep_w_kernel<<<(On * Kn + 255) / 256, 256, 0, stream>>>(w_t, w_l, w_r, wcT);
  tree_conv_kernel<<<(Bn * Nn) / MT, 256, 0, stream>>>(nodes, children, wcT, bias, out);
}

// Round 2
// 135.614 us; speedup vs baseline: 1.0875x; 1.0875x over previous
//
#include <hip/hip_runtime.h>

typedef unsigned short ushort_t;
typedef __attribute__((ext_vector_type(8))) short short8;
typedef __attribute__((ext_vector_type(4))) short short4v;
typedef __attribute__((ext_vector_type(4))) float float4v;

#define Bn 32
#define Nn 2048
#define Cn 8
#define Fn 128
#define On 128
#define Kn 384   // 3*F
#define MT 32    // rows per workgroup (halved vs R1: LDS 24.5 KiB -> ~2x occupancy)
#define LDSK 392 // Kn + 8 pad (shorts); row stride 784 B

// float -> bf16 bits, round-to-nearest-even
__device__ __forceinline__ ushort_t f2bf(float x) {
  unsigned u = __float_as_uint(x);
  u += 0x7fffu + ((u >> 16) & 1u);
  return (ushort_t)(u >> 16);
}

// Pack concat(w_t, w_r, w_l) transposed: wcT[o][k], k in [0,384), bf16 bits.
__global__ void prep_w_kernel(const float* __restrict__ w_t,
                              const float* __restrict__ w_l,
                              const float* __restrict__ w_r,
                              ushort_t* __restrict__ wcT) {
  int i = blockIdx.x * blockDim.x + threadIdx.x;
  if (i >= On * Kn) return;
  int o = i / Kn;
  int k = i - o * Kn;
  const float* src = (k < Fn) ? w_t : (k < 2 * Fn) ? w_r : w_l;
  int f = k & (Fn - 1);
  wcT[i] = f2bf(src[f * On + o]);
}

__global__ __launch_bounds__(256)
void tree_conv_kernel(const float* __restrict__ nodes,
                      const int* __restrict__ children,
                      const ushort_t* __restrict__ wcT,
                      const float* __restrict__ bias,
                      float* __restrict__ out) {
  __shared__ __align__(16) ushort_t agg[MT * LDSK];

  const int tid = threadIdx.x;

  // XCD-locality swizzle: with round-robin block->XCD (%8), this gives XCD k
  // the contiguous original-block range [k*256, (k+1)*256) = batches 4k..4k+3
  // (4 MB of nodes -> fits the XCD's 4 MiB L2).
  const int sb = ((blockIdx.x & 7) << 8) | (blockIdx.x >> 3);

  // ---------------- Phase A: build bf16 agg tile [32 rows][384] in LDS ------
  {
    const int row = tid >> 3;            // 0..31
    const int fc = (tid & 7) * 16;       // f-chunk start (16 floats per thread)
    const int g = sb * MT + row;         // global row in [0, 65536)
    const int base_row = g & ~(Nn - 1);  // b * Nn

    const int4* chv = (const int4*)(children + g * Cn);
    int4 ca = chv[0], cb = chv[1];
    int idx[Cn] = {ca.x, ca.y, ca.z, ca.w, cb.x, cb.y, cb.z, cb.w};

    int ns = 0;
#pragma unroll
    for (int c = 0; c < Cn; ++c) ns += (idx[c] != 0);
    const float denom = (ns > 1) ? (float)(ns - 1) : 1.0f;

    float crv[Cn], clv[Cn];
#pragma unroll
    for (int c = 0; c < Cn; ++c) {
      float m = (idx[c] != 0) ? 1.0f : 0.0f;
      float cr0 = (ns == 1) ? ((c == 0) ? 0.5f : 0.0f) : ((float)c / denom);
      float cr = cr0 * m;          // zero coeff when child idx==0 (zero-vector)
      crv[c] = cr;
      clv[c] = (1.0f - cr) * m;
    }

    ushort_t* arow = agg + row * LDSK;

    // self -> k [0,128)
    const float4v* sp = (const float4v*)(nodes + (size_t)g * Fn + fc);
    float4v s0 = sp[0], s1 = sp[1], s2 = sp[2], s3 = sp[3];
    {
      short8 pk0 = {(short)f2bf(s0.x), (short)f2bf(s0.y), (short)f2bf(s0.z), (short)f2bf(s0.w),
                    (short)f2bf(s1.x), (short)f2bf(s1.y), (short)f2bf(s1.z), (short)f2bf(s1.w)};
      short8 pk1 = {(short)f2bf(s2.x), (short)f2bf(s2.y), (short)f2bf(s2.z), (short)f2bf(s2.w),
                    (short)f2bf(s3.x), (short)f2bf(s3.y), (short)f2bf(s3.z), (short)f2bf(s3.w)};
      *(short8*)(arow + fc) = pk0;
      *(short8*)(arow + fc + 8) = pk1;
    }

    // children -> r (k [128,256)) and l (k [256,384))
    float4v r[4], l[4];
    const float4v z = {0.f, 0.f, 0.f, 0.f};
#pragma unroll
    for (int j = 0; j < 4; ++j) { r[j] = z; l[j] = z; }

#pragma unroll
    for (int c = 0; c < Cn; ++c) {
      // idx==0 reads batch row 0, but coeffs are 0 -> contributes 0
      const float4v* cp =
          (const float4v*)(nodes + (size_t)(base_row + idx[c]) * Fn + fc);
      const float cr = crv[c], cl = clv[c];
#pragma unroll
      for (int j = 0; j < 4; ++j) {
        float4v v = cp[j];
        r[j] += cr * v;
        l[j] += cl * v;
      }
    }

    {
      short8 pk0 = {(short)f2bf(r[0].x), (short)f2bf(r[0].y), (short)f2bf(r[0].z), (short)f2bf(r[0].w),
                    (short)f2bf(r[1].x), (short)f2bf(r[1].y), (short)f2bf(r[1].z), (short)f2bf(r[1].w)};
      short8 pk1 = {(short)f2bf(r[2].x), (short)f2bf(r[2].y), (short)f2bf(r[2].z), (short)f2bf(r[2].w),
                    (short)f2bf(r[3].x), (short)f2bf(r[3].y), (short)f2bf(r[3].z), (short)f2bf(r[3].w)};
      *(short8*)(arow + Fn + fc) = pk0;
      *(short8*)(arow + Fn + fc + 8) = pk1;
      short8 pk2 = {(short)f2bf(l[0].x), (short)f2bf(l[0].y), (short)f2bf(l[0].z), (short)f2bf(l[0].w),
                    (short)f2bf(l[1].x), (short)f2bf(l[1].y), (short)f2bf(l[1].z), (short)f2bf(l[1].w)};
      short8 pk3 = {(short)f2bf(l[2].x), (short)f2bf(l[2].y), (short)f2bf(l[2].z), (short)f2bf(l[2].w),
                    (short)f2bf(l[3].x), (short)f2bf(l[3].y), (short)f2bf(l[3].z), (short)f2bf(l[3].w)};
      *(short8*)(arow + 2 * Fn + fc) = pk2;
      *(short8*)(arow + 2 * Fn + fc + 8) = pk3;
    }
  }

  // ---------------- B fragments: held in registers, reused over subtiles ----
  const int lane = tid & 63;
  const int wave = tid >> 6;   // 0..3, owns cols [wave*32, wave*32+32)
  const int l15 = lane & 15;
  const int quad = lane >> 4;

  short8 bfrag[2][12];
#pragma unroll
  for (int ct = 0; ct < 2; ++ct) {
    const ushort_t* bp = wcT + (size_t)(wave * 32 + ct * 16 + l15) * Kn + quad * 8;
#pragma unroll
    for (int ks = 0; ks < 12; ++ks)
      bfrag[ct][ks] = *(const short8*)(bp + ks * 32);
  }

  const float bias0 = bias[wave * 32 + l15];
  const float bias1 = bias[wave * 32 + 16 + l15];

  __syncthreads();

  // ---------------- Phase B: MFMA over 2 row-subtiles of 16 ----------------
#pragma unroll 1
  for (int st = 0; st < 2; ++st) {
    const ushort_t* ar = agg + (st * 16 + l15) * LDSK + quad * 8;
    float4v acc0 = {0.f, 0.f, 0.f, 0.f};
    float4v acc1 = {0.f, 0.f, 0.f, 0.f};
#pragma unroll
    for (int ks = 0; ks < 12; ++ks) {
      short8 af = *(const short8*)(ar + ks * 32);
      acc0 = __builtin_amdgcn_mfma_f32_16x16x32_bf16(af, bfrag[0][ks], acc0, 0, 0, 0);
      acc1 = __builtin_amdgcn_mfma_f32_16x16x32_bf16(af, bfrag[1][ks], acc1, 0, 0, 0);
    }
    const int grow0 = sb * MT + st * 16 + quad * 4;
    const int col0 = wave * 32 + l15;
#pragma unroll
    for (int r2 = 0; r2 < 4; ++r2) {
      float v0 = acc0[r2] + bias0;
      float v1 = acc1[r2] + bias1;
      out[(size_t)(grow0 + r2) * On + col0] = fmaxf(v0, 0.f);
      out[(size_t)(grow0 + r2) * On + col0 + 16] = fmaxf(v1, 0.f);
    }
  }
}

extern "C" void kernel_launch(void* const* d_in, const int* in_sizes, int n_in,
                              void* d_out, int out_size, void* d_ws, size_t ws_size,
                              hipStream_t stream) {
  const float* nodes = (const float*)d_in[0];
  const int* children = (const int*)d_in[1];
  const float* w_t = (const float*)d_in[2];
  const float* w_l = (const float*)d_in[3];
  const float* w_r = (const float*)d_in[4];
  const float* bias = (const float*)d_in[5];
  float* out = (float*)d_out;
  ushort_t* wcT = (ushort_t*)d_ws;  // 128*384*2 = 96 KiB

  prep_w_kernel<<<(On * Kn + 255) / 256, 256, 0, stream>>>(w_t, w_l, w_r, wcT);
  tree_conv_kernel<<<(Bn * Nn) / MT, 256, 0, stream>>>(nodes, children, wcT, bias, out);
}

// Round 4
// 122.921 us; speedup vs baseline: 1.1998x; 1.1033x over previous
//
#include <hip/hip_runtime.h>

typedef unsigned short ushort_t;
typedef __attribute__((ext_vector_type(8))) short short8;
typedef __attribute__((ext_vector_type(4))) short short4v;
typedef __attribute__((ext_vector_type(4))) float float4v;

#define Bn 32
#define Nn 2048
#define Cn 8
#define Fn 128
#define On 128
#define Kn 384   // 3*F
#define MT 32    // rows per workgroup
#define LDSK 392 // Kn + 8 pad (shorts); row stride 784 B

// float -> bf16 bits, round-to-nearest-even
__device__ __forceinline__ ushort_t f2bf(float x) {
  unsigned u = __float_as_uint(x);
  u += 0x7fffu + ((u >> 16) & 1u);
  return (ushort_t)(u >> 16);
}

// Pack concat(w_t, w_r, w_l) directly in MFMA B-fragment order:
// element (((w*2+ct)*12+ks)*64 + lane)*8 + j  holds  W[k][col], where
//   col = w*32 + ct*16 + (lane&15),  k = (lane>>4)*8 + ks*32 + j.
// Phase B then loads B fragments as fully-coalesced 1KB-per-wave short8 loads.
__global__ void prep_w_kernel(const float* __restrict__ w_t,
                              const float* __restrict__ w_l,
                              const float* __restrict__ w_r,
                              ushort_t* __restrict__ wsw) {
  int t = blockIdx.x * blockDim.x + threadIdx.x; // one short8 per thread
  if (t >= 6144) return;                         // 6144*8 = 49152 elements
  int lane = t & 63;
  int r = t >> 6;        // 0..95
  int ks = r % 12;
  int q = r / 12;        // 0..7
  int ct = q & 1;
  int w = q >> 1;
  int col = w * 32 + ct * 16 + (lane & 15);
  int kbase = ((lane >> 4) * 8) + ks * 32;
  ushort_t* dst = wsw + (size_t)t * 8;
#pragma unroll
  for (int j = 0; j < 8; ++j) {
    int k = kbase + j;
    const float* src = (k < Fn) ? w_t : (k < 2 * Fn) ? w_r : w_l;
    int f = k & (Fn - 1);
    dst[j] = f2bf(src[f * On + col]);
  }
}

__global__ __launch_bounds__(256)
void tree_conv_kernel(const float* __restrict__ nodes,
                      const int* __restrict__ children,
                      const ushort_t* __restrict__ wsw,
                      const float* __restrict__ bias,
                      float* __restrict__ out) {
  __shared__ __align__(16) ushort_t agg[MT * LDSK];

  const int tid = threadIdx.x;

  // XCD-locality swizzle: round-robin block->XCD (%8) => XCD k owns batches
  // 4k..4k+3 (4 MB of nodes -> fits the XCD's 4 MiB L2).
  const int sb = ((blockIdx.x & 7) << 8) | (blockIdx.x >> 3);

  // ---------------- Phase A: build bf16 agg tile [32 rows][384] in LDS ------
  // 8 groups of 32 lanes; group handles rows {it*8+grp}; each lane owns one
  // contiguous float4 of F => every gather instr is fully coalesced
  // (32 lanes x 16 B = 512 B contiguous per row).
  {
    const int grp = tid >> 5;  // 0..7
    const int ln = tid & 31;   // 0..31 -> floats [ln*4, ln*4+4)

#pragma unroll
    for (int it = 0; it < 4; ++it) {
      const int row = it * 8 + grp;
      const int g = sb * MT + row;
      const int base_row = g & ~(Nn - 1);  // b * Nn

      const int4* chv = (const int4*)(children + (size_t)g * Cn);
      int4 ca = chv[0], cb = chv[1];
      int idx[Cn] = {ca.x, ca.y, ca.z, ca.w, cb.x, cb.y, cb.z, cb.w};

      int ns = 0;
#pragma unroll
      for (int c = 0; c < Cn; ++c) ns += (idx[c] != 0);
      const float denom = (ns > 1) ? (float)(ns - 1) : 1.0f;

      float crv[Cn], clv[Cn];
#pragma unroll
      for (int c = 0; c < Cn; ++c) {
        float m = (idx[c] != 0) ? 1.0f : 0.0f;
        float cr0 = (ns == 1) ? ((c == 0) ? 0.5f : 0.0f) : ((float)c / denom);
        float cr = cr0 * m;  // zero coeff when child idx==0 (zero-vector)
        crv[c] = cr;
        clv[c] = (1.0f - cr) * m;
        // fault-proofing: clamp index into [0,Nn) so even a replay with
        // non-pristine `children` cannot generate an OOB address (coeff math
        // is unchanged for in-range inputs; mask used idx!=0 before clamp).
        idx[c] &= (Nn - 1);
      }

      // self (coalesced)
      const float4v sv = *((const float4v*)(nodes + (size_t)g * Fn) + ln);

      // gather-accumulate r,l (each load coalesced across the 32-lane group)
      float4v rr = {0.f, 0.f, 0.f, 0.f};
      float4v ll = {0.f, 0.f, 0.f, 0.f};
#pragma unroll
      for (int c = 0; c < Cn; ++c) {
        const float4v v =
            *((const float4v*)(nodes + (size_t)(base_row + idx[c]) * Fn) + ln);
        rr += crv[c] * v;
        ll += clv[c] * v;
      }

      ushort_t* arow = agg + row * LDSK;
      short4v ps = {(short)f2bf(sv.x), (short)f2bf(sv.y),
                    (short)f2bf(sv.z), (short)f2bf(sv.w)};
      short4v pr = {(short)f2bf(rr.x), (short)f2bf(rr.y),
                    (short)f2bf(rr.z), (short)f2bf(rr.w)};
      short4v pl = {(short)f2bf(ll.x), (short)f2bf(ll.y),
                    (short)f2bf(ll.z), (short)f2bf(ll.w)};
      *(short4v*)(arow + ln * 4) = ps;
      *(short4v*)(arow + Fn + ln * 4) = pr;
      *(short4v*)(arow + 2 * Fn + ln * 4) = pl;
    }
  }

  __syncthreads();

  // ---------------- Phase B: MFMA; B streamed coalesced from wsw ------------
  const int lane = tid & 63;
  const int wave = tid >> 6;  // 0..3
  const int l15 = lane & 15;
  const int quad = lane >> 4;

#pragma unroll
  for (int ct = 0; ct < 2; ++ct) {
    // 12 B fragments for this col-tile: coalesced 1KB-per-wave loads, L2-hot.
    const short8* bp = (const short8*)wsw + ((wave * 2 + ct) * 12) * 64 + lane;
    short8 bfrag[12];
#pragma unroll
    for (int ks = 0; ks < 12; ++ks) bfrag[ks] = bp[ks * 64];

    const int col = wave * 32 + ct * 16 + l15;
    const float bb = bias[col];

#pragma unroll
    for (int st = 0; st < 2; ++st) {
      const ushort_t* ar = agg + (st * 16 + l15) * LDSK + quad * 8;
      float4v acc = {0.f, 0.f, 0.f, 0.f};
#pragma unroll
      for (int ks = 0; ks < 12; ++ks) {
        short8 af = *(const short8*)(ar + ks * 32);
        acc = __builtin_amdgcn_mfma_f32_16x16x32_bf16(af, bfrag[ks], acc, 0, 0, 0);
      }
      const int grow0 = sb * MT + st * 16 + quad * 4;
#pragma unroll
      for (int r2 = 0; r2 < 4; ++r2) {
        out[(size_t)(grow0 + r2) * On + col] = fmaxf(acc[r2] + bb, 0.f);
      }
    }
  }
}

extern "C" void kernel_launch(void* const* d_in, const int* in_sizes, int n_in,
                              void* d_out, int out_size, void* d_ws, size_t ws_size,
                              hipStream_t stream) {
  const float* nodes = (const float*)d_in[0];
  const int* children = (const int*)d_in[1];
  const float* w_t = (const float*)d_in[2];
  const float* w_l = (const float*)d_in[3];
  const float* w_r = (const float*)d_in[4];
  const float* bias = (const float*)d_in[5];
  float* out = (float*)d_out;
  ushort_t* wsw = (ushort_t*)d_ws;  // 49152 bf16 = 96 KiB, fragment-swizzled

  prep_w_kernel<<<24, 256, 0, stream>>>(w_t, w_l, w_r, wsw);
  tree_conv_kernel<<<(Bn * Nn) / MT, 256, 0, stream>>>(nodes, children, wsw, bias, out);
}

// Round 5
// 116.398 us; speedup vs baseline: 1.2671x; 1.0560x over previous
//
#include <hip/hip_runtime.h>

typedef unsigned short ushort_t;
typedef __attribute__((ext_vector_type(8))) short short8;
typedef __attribute__((ext_vector_type(4))) short short4v;
typedef __attribute__((ext_vector_type(4))) float float4v;

#define Bn 32
#define Nn 2048
#define Cn 8
#define Fn 128
#define On 128
#define Kn 384   // 3*F
#define MT 16    // rows per workgroup (16: LDS 12.25 KiB -> 13 blocks/CU headroom)
#define LDSK 392 // Kn + 8 pad (shorts); row stride 784 B

// float -> bf16 bits, round-to-nearest-even
__device__ __forceinline__ ushort_t f2bf(float x) {
  unsigned u = __float_as_uint(x);
  u += 0x7fffu + ((u >> 16) & 1u);
  return (ushort_t)(u >> 16);
}

// Pack concat(w_t, w_r, w_l) directly in MFMA B-fragment order:
// fragment q (0..7), step ks (0..11): element ((q*12+ks)*64 + lane)*8 + j
// holds W[k][col] with col = q*16 + (lane&15), k = (lane>>4)*8 + ks*32 + j.
__global__ void prep_w_kernel(const float* __restrict__ w_t,
                              const float* __restrict__ w_l,
                              const float* __restrict__ w_r,
                              ushort_t* __restrict__ wsw) {
  int t = blockIdx.x * blockDim.x + threadIdx.x; // one short8 per thread
  if (t >= 6144) return;                         // 6144*8 = 49152 elements
  int lane = t & 63;
  int r = t >> 6;        // 0..95
  int ks = r % 12;
  int q = r / 12;        // 0..7
  int col = q * 16 + (lane & 15);
  int kbase = ((lane >> 4) * 8) + ks * 32;
  ushort_t* dst = wsw + (size_t)t * 8;
#pragma unroll
  for (int j = 0; j < 8; ++j) {
    int k = kbase + j;
    const float* src = (k < Fn) ? w_t : (k < 2 * Fn) ? w_r : w_l;
    int f = k & (Fn - 1);
    dst[j] = f2bf(src[f * On + col]);
  }
}

__global__ __launch_bounds__(128, 5)
void tree_conv_kernel(const float* __restrict__ nodes,
                      const int* __restrict__ children,
                      const ushort_t* __restrict__ wsw,
                      const float* __restrict__ bias,
                      float* __restrict__ out) {
  __shared__ __align__(16) ushort_t agg[MT * LDSK];

  const int tid = threadIdx.x;

  // XCD-locality swizzle: round-robin block->XCD (%8) => XCD k owns batches
  // 4k..4k+3 (4 MB of nodes -> fits the XCD's 4 MiB L2).
  const int sb = ((blockIdx.x & 7) << 9) | (blockIdx.x >> 3);

  // ---------------- Phase A: build bf16 agg tile [16 rows][384] in LDS ------
  // 4 groups of 32 lanes; group g handles rows {it*4+g}; each lane owns one
  // contiguous float4 of F => every gather instr is fully coalesced.
  {
    const int grp = tid >> 5;  // 0..3
    const int ln = tid & 31;   // 0..31 -> floats [ln*4, ln*4+4)

    // Hoist all children loads (independent) so the compiler can overlap the
    // per-row gather chains across iterations.
    int4 ca[4], cb[4];
#pragma unroll
    for (int it = 0; it < 4; ++it) {
      const int g = sb * MT + it * 4 + grp;
      const int4* chv = (const int4*)(children + (size_t)g * Cn);
      ca[it] = chv[0];
      cb[it] = chv[1];
    }

#pragma unroll
    for (int it = 0; it < 4; ++it) {
      const int row = it * 4 + grp;
      const int g = sb * MT + row;
      const int base_row = g & ~(Nn - 1);  // b * Nn

      int idx[Cn] = {ca[it].x, ca[it].y, ca[it].z, ca[it].w,
                     cb[it].x, cb[it].y, cb[it].z, cb[it].w};

      int ns = 0;
#pragma unroll
      for (int c = 0; c < Cn; ++c) ns += (idx[c] != 0);
      const float denom = (ns > 1) ? (float)(ns - 1) : 1.0f;

      float crv[Cn], clv[Cn];
#pragma unroll
      for (int c = 0; c < Cn; ++c) {
        float m = (idx[c] != 0) ? 1.0f : 0.0f;
        float cr0 = (ns == 1) ? ((c == 0) ? 0.5f : 0.0f) : ((float)c / denom);
        float cr = cr0 * m;  // zero coeff when child idx==0 (zero-vector)
        crv[c] = cr;
        clv[c] = (1.0f - cr) * m;
        // fault-proofing: clamp so a replay with non-pristine `children`
        // cannot fault (no effect on in-range pristine inputs).
        idx[c] &= (Nn - 1);
      }

      // self (coalesced, independent of children)
      const float4v sv = *((const float4v*)(nodes + (size_t)g * Fn) + ln);

      // gather-accumulate r,l (each load coalesced across the 32-lane group)
      float4v rr = {0.f, 0.f, 0.f, 0.f};
      float4v ll = {0.f, 0.f, 0.f, 0.f};
#pragma unroll
      for (int c = 0; c < Cn; ++c) {
        const float4v v =
            *((const float4v*)(nodes + (size_t)(base_row + idx[c]) * Fn) + ln);
        rr += crv[c] * v;
        ll += clv[c] * v;
      }

      ushort_t* arow = agg + row * LDSK;
      short4v ps = {(short)f2bf(sv.x), (short)f2bf(sv.y),
                    (short)f2bf(sv.z), (short)f2bf(sv.w)};
      short4v pr = {(short)f2bf(rr.x), (short)f2bf(rr.y),
                    (short)f2bf(rr.z), (short)f2bf(rr.w)};
      short4v pl = {(short)f2bf(ll.x), (short)f2bf(ll.y),
                    (short)f2bf(ll.z), (short)f2bf(ll.w)};
      *(short4v*)(arow + ln * 4) = ps;
      *(short4v*)(arow + Fn + ln * 4) = pr;
      *(short4v*)(arow + 2 * Fn + ln * 4) = pl;
    }
  }

  __syncthreads();

  // ---------------- Phase B: MFMA; B streamed coalesced from wsw ------------
  const int lane = tid & 63;
  const int wave = tid >> 6;  // 0..1, owns col-tiles q = wave*4 .. wave*4+3
  const int l15 = lane & 15;
  const int quad = lane >> 4;

#pragma unroll
  for (int ct = 0; ct < 4; ++ct) {
    const int q = wave * 4 + ct;
    // 12 B fragments for this col-tile: coalesced 1KB-per-wave loads, L2-hot.
    const short8* bp = (const short8*)wsw + (q * 12) * 64 + lane;
    short8 bfrag[12];
#pragma unroll
    for (int ks = 0; ks < 12; ++ks) bfrag[ks] = bp[ks * 64];

    const int col = q * 16 + l15;
    const float bb = bias[col];

    const ushort_t* ar = agg + l15 * LDSK + quad * 8;
    float4v acc = {0.f, 0.f, 0.f, 0.f};
#pragma unroll
    for (int ks = 0; ks < 12; ++ks) {
      short8 af = *(const short8*)(ar + ks * 32);
      acc = __builtin_amdgcn_mfma_f32_16x16x32_bf16(af, bfrag[ks], acc, 0, 0, 0);
    }
    const int grow0 = sb * MT + quad * 4;
#pragma unroll
    for (int r2 = 0; r2 < 4; ++r2) {
      out[(size_t)(grow0 + r2) * On + col] = fmaxf(acc[r2] + bb, 0.f);
    }
  }
}

extern "C" void kernel_launch(void* const* d_in, const int* in_sizes, int n_in,
                              void* d_out, int out_size, void* d_ws, size_t ws_size,
                              hipStream_t stream) {
  const float* nodes = (const float*)d_in[0];
  const int* children = (const int*)d_in[1];
  const float* w_t = (const float*)d_in[2];
  const float* w_l = (const float*)d_in[3];
  const float* w_r = (const float*)d_in[4];
  const float* bias = (const float*)d_in[5];
  float* out = (float*)d_out;
  ushort_t* wsw = (ushort_t*)d_ws;  // 49152 bf16 = 96 KiB, fragment-swizzled

  prep_w_kernel<<<24, 256, 0, stream>>>(w_t, w_l, w_r, wsw);
  tree_conv_kernel<<<(Bn * Nn) / MT, 128, 0, stream>>>(nodes, children, wsw, bias, out);
}